// Round 3
// baseline (483.776 us; speedup 1.0000x reference)
//
#include <hip/hip_runtime.h>

// Problem constants (from reference)
#define N_TOT   262144
#define KCODES  1024
#define DIM     256
#define DECAY   0.99f
#define OMDECAY 0.01f      // (1.0f - 0.99f) == 0.01f in f32
#define EPS     1e-5f

// ---------------------------------------------------------------------------
// Pass 1: histogram of indices -> counts[K] (int atomics, low contention)
// ---------------------------------------------------------------------------
__global__ void k_hist(const int* __restrict__ idx, int* __restrict__ counts) {
    for (int i = blockIdx.x * blockDim.x + threadIdx.x; i < N_TOT;
         i += gridDim.x * blockDim.x) {
        atomicAdd(&counts[idx[i]], 1);
    }
}

// ---------------------------------------------------------------------------
// Pass 2: single block of K threads.
//   - exclusive prefix sum of counts -> offsets, cursor
//   - new_cs = cs*DECAY + (1-DECAY)*counts  -> d_out[0:K]
//   - n = sum(new_cs)  (LDS tree reduce)
//   - smoothed[k] = (new_cs+EPS)/(n+K*EPS)*n
// ---------------------------------------------------------------------------
__global__ void k_scan(const int* __restrict__ counts,
                       const float* __restrict__ cluster_size,
                       int* __restrict__ offsets,
                       int* __restrict__ cursor,
                       float* __restrict__ smoothed,
                       float* __restrict__ out_cs) {
    __shared__ int   sc[KCODES];
    __shared__ float sf[KCODES];
    const int t = threadIdx.x;

    const int c = counts[t];
    sc[t] = c;
    __syncthreads();
    // Hillis-Steele inclusive scan over 1024 elements
    for (int off = 1; off < KCODES; off <<= 1) {
        int v = (t >= off) ? sc[t - off] : 0;
        __syncthreads();
        sc[t] += v;
        __syncthreads();
    }
    const int excl = sc[t] - c;
    offsets[t] = excl;
    cursor[t]  = excl;

    const float ncs = cluster_size[t] * DECAY + OMDECAY * (float)c;
    out_cs[t] = ncs;
    sf[t] = ncs;
    __syncthreads();
    for (int off = KCODES / 2; off > 0; off >>= 1) {
        if (t < off) sf[t] += sf[t + off];
        __syncthreads();
    }
    const float n = sf[0];
    smoothed[t] = (ncs + EPS) / (n + (float)KCODES * EPS) * n;
}

// ---------------------------------------------------------------------------
// Pass 3: bucket row ids into segment-sorted order (counting sort, ids only)
// ---------------------------------------------------------------------------
__global__ void k_scatter(const int* __restrict__ idx,
                          int* __restrict__ cursor,
                          int* __restrict__ sorted) {
    for (int i = blockIdx.x * blockDim.x + threadIdx.x; i < N_TOT;
         i += gridDim.x * blockDim.x) {
        int pos = atomicAdd(&cursor[idx[i]], 1);
        sorted[pos] = i;
    }
}

// ---------------------------------------------------------------------------
// Pass 4: one block per code k; thread t owns column t (coalesced 1KB rows).
// Sums the segment with zero atomics, then fuses EMA + normalize epilogue.
// ---------------------------------------------------------------------------
__global__ void __launch_bounds__(DIM)
k_sum(const float* __restrict__ enc,
      const float* __restrict__ embed_avg,
      const int* __restrict__ counts,
      const int* __restrict__ offsets,
      const int* __restrict__ sorted,
      const float* __restrict__ smoothed,
      float* __restrict__ out) {
    const int k = blockIdx.x;
    const int t = threadIdx.x;          // 0..255 = column
    const int start = offsets[k];
    const int cnt   = counts[k];

    float acc = 0.f;
    int j = 0;
    // Unroll 8: keep 8 independent 1KB row-gathers in flight per wave.
    for (; j + 8 <= cnt; j += 8) {
        int r0 = sorted[start + j + 0];
        int r1 = sorted[start + j + 1];
        int r2 = sorted[start + j + 2];
        int r3 = sorted[start + j + 3];
        int r4 = sorted[start + j + 4];
        int r5 = sorted[start + j + 5];
        int r6 = sorted[start + j + 6];
        int r7 = sorted[start + j + 7];
        float a0 = enc[(size_t)r0 * DIM + t];
        float a1 = enc[(size_t)r1 * DIM + t];
        float a2 = enc[(size_t)r2 * DIM + t];
        float a3 = enc[(size_t)r3 * DIM + t];
        float a4 = enc[(size_t)r4 * DIM + t];
        float a5 = enc[(size_t)r5 * DIM + t];
        float a6 = enc[(size_t)r6 * DIM + t];
        float a7 = enc[(size_t)r7 * DIM + t];
        acc += a0; acc += a1; acc += a2; acc += a3;
        acc += a4; acc += a5; acc += a6; acc += a7;
    }
    for (; j < cnt; ++j) {
        int r = sorted[start + j];
        acc += enc[(size_t)r * DIM + t];
    }

    const float ea = embed_avg[(size_t)k * DIM + t] * DECAY + OMDECAY * acc;
    out[KCODES + (size_t)k * DIM + t] = ea;
    out[KCODES + (size_t)KCODES * DIM + (size_t)k * DIM + t] = ea / smoothed[k];
}

// ---------------------------------------------------------------------------
extern "C" void kernel_launch(void* const* d_in, const int* in_sizes, int n_in,
                              void* d_out, int out_size, void* d_ws, size_t ws_size,
                              hipStream_t stream) {
    const int*   idx = (const int*)  d_in[0];   // indices      [N]
    const float* enc = (const float*)d_in[1];   // encodings    [N,D]
    const float* cs  = (const float*)d_in[2];   // cluster_size [K]
    const float* ea  = (const float*)d_in[3];   // embed_avg    [K,D]
    float* out = (float*)d_out;                 // [K] ++ [K,D] ++ [K,D]

    char* ws = (char*)d_ws;
    int*   counts   = (int*)  (ws);
    int*   offsets  = (int*)  (ws + 1 * KCODES * 4);
    int*   cursor   = (int*)  (ws + 2 * KCODES * 4);
    float* smoothed = (float*)(ws + 3 * KCODES * 4);
    int*   sorted   = (int*)  (ws + 4 * KCODES * 4);   // N ints

    hipMemsetAsync(counts, 0, KCODES * sizeof(int), stream);
    k_hist   <<<1024, 256, 0, stream>>>(idx, counts);
    k_scan   <<<1, KCODES, 0, stream>>>(counts, cs, offsets, cursor, smoothed, out);
    k_scatter<<<1024, 256, 0, stream>>>(idx, cursor, sorted);
    k_sum    <<<KCODES, DIM, 0, stream>>>(enc, ea, counts, offsets, sorted, smoothed, out);
}